// Round 1
// baseline (3607.220 us; speedup 1.0000x reference)
//
#include <hip/hip_runtime.h>
#include <math.h>

// Problem constants
#define NB 32768
#define NC 100
#define NK 8
#define ND 512
// X layout in workspace: rows 0..799 = Pn, 800..899 = centers, 900..999 = bvec
// ws = 0.5/8, wo = 0.5/99, ridge = 0.1
// A0 = ridge*I + wo*C^T C  (C = centers, 100x512)
// A_c = A0 + V_c diag(ws..ws,-wo) V_c^T,  V_c = [p_c1..p_c8, c_c]
// Woodbury twice: only a 100x100 inverse + small GEMMs + 9x9 solves needed.

__device__ __forceinline__ float warpReduceSum(float v) {
#pragma unroll
    for (int off = 32; off > 0; off >>= 1) v += __shfl_xor(v, off);
    return v;
}

__device__ float blockReduceSum256(float v, float* red) {
    int tid = threadIdx.x;
    v = warpReduceSum(v);
    __syncthreads();
    if ((tid & 63) == 0) red[tid >> 6] = v;
    __syncthreads();
    return red[0] + red[1] + red[2] + red[3];
}

// P1: per class: normalize 8 protos -> Pn (X rows), centers, b_same (into bvec)
__global__ void k_prep_class(const float* __restrict__ protos, float* __restrict__ X) {
    __shared__ float red[4];
    int c = blockIdx.x;
    int tid = threadIdx.x;
    const float eps = 1e-8f;
    float pv0[NK], pv1[NK];
#pragma unroll
    for (int k = 0; k < NK; ++k) {
        pv0[k] = protos[(c * NK + k) * ND + tid];
        pv1[k] = protos[(c * NK + k) * ND + tid + 256];
    }
    float sv0 = 0.f, sv1 = 0.f;
#pragma unroll
    for (int k = 0; k < NK; ++k) {
        float ss = blockReduceSum256(pv0[k] * pv0[k] + pv1[k] * pv1[k], red);
        float inv = 1.0f / fmaxf(sqrtf(ss), eps);
        pv0[k] *= inv; pv1[k] *= inv;
        X[(c * NK + k) * ND + tid] = pv0[k];
        X[(c * NK + k) * ND + tid + 256] = pv1[k];
        sv0 += pv0[k]; sv1 += pv1[k];
    }
    float ssum = blockReduceSum256(sv0 * sv0 + sv1 * sv1, red);
    float mnorm = sqrtf(ssum) * 0.125f;                 // ||mean||
    float cinv = 0.125f / fmaxf(mnorm, eps);            // mean/max(||mean||,eps)
    float* centers = X + 800 * ND;
    centers[c * ND + tid] = sv0 * cinv;
    centers[c * ND + tid + 256] = sv1 * cinv;
    const float ws = 0.5f / 8.0f;
    float* bvec = X + 900 * ND;
    bvec[c * ND + tid] = ws * sv0;                      // b_same = ws * sum(Pn)
    bvec[c * ND + tid + 256] = ws * sv1;
}

// P2a: csum[d] = sum_c centers[c][d]
__global__ void k_csum(const float* __restrict__ X, float* __restrict__ csum) {
    int d = blockIdx.x * blockDim.x + threadIdx.x;
    const float* centers = X + 800 * ND;
    float s = 0.f;
    for (int c = 0; c < NC; ++c) s += centers[c * ND + d];
    csum[d] = s;
}

// P2b: bvec += -wo*(csum - centers_c)
__global__ void k_bopp(float* __restrict__ X, const float* __restrict__ csum) {
    int c = blockIdx.x, tid = threadIdx.x;
    const float wo = 0.5f / 99.0f;
    const float* centers = X + 800 * ND;
    float* bvec = X + 900 * ND;
    for (int d = tid; d < ND; d += 256)
        bvec[c * ND + d] -= wo * (csum[d] - centers[c * ND + d]);
}

// P3: Ahat = (ridge/wo) I + C C^T   (100x100)
__global__ void k_gram(const float* __restrict__ X, float* __restrict__ Ahat) {
    __shared__ float cs[ND];
    int i = blockIdx.x, tid = threadIdx.x;
    const float* centers = X + 800 * ND;
    for (int d = tid; d < ND; d += 128) cs[d] = centers[i * ND + d];
    __syncthreads();
    if (tid < NC) {
        const float* cj = centers + tid * ND;
        float s = 0.f;
        for (int d = 0; d < ND; ++d) s += cs[d] * cj[d];
        if (tid == i) s += 0.1f * 99.0f / 0.5f;  // ridge/wo = 19.8
        Ahat[i * NC + tid] = s;
    }
}

// P4: in-place Gauss-Jordan inverse of 100x100 (SPD, diag ~20 -> no pivoting)
__global__ void k_inv(const float* __restrict__ Ahat, float* __restrict__ Mint) {
    __shared__ float A[NC * NC];
    __shared__ float prow[NC];
    __shared__ float fcol[NC];
    int tid = threadIdx.x;
    for (int idx = tid; idx < NC * NC; idx += 256) A[idx] = Ahat[idx];
    __syncthreads();
    for (int p = 0; p < NC; ++p) {
        float ipiv = 1.0f / A[p * NC + p];
        for (int j = tid; j < NC; j += 256) prow[j] = (j == p) ? ipiv : A[p * NC + j] * ipiv;
        for (int r = tid; r < NC; r += 256) fcol[r] = A[r * NC + p];
        __syncthreads();
        for (int idx = tid; idx < NC * NC; idx += 256) {
            int r = idx / NC, j = idx - r * NC;
            float pr = prow[j];
            A[idx] = (r == p) ? pr : ((j == p) ? (-fcol[r] * ipiv) : (A[idx] - fcol[r] * pr));
        }
        __syncthreads();
    }
    for (int idx = tid; idx < NC * NC; idx += 256) Mint[idx] = A[idx];
}

// P5a: T1[i][j] = centers_i . X_j   (100 x 1000)
__global__ void k_T1(const float* __restrict__ X, float* __restrict__ T1) {
    __shared__ float xs[ND];
    int j = blockIdx.x, tid = threadIdx.x;
    reinterpret_cast<float4*>(xs)[tid] = reinterpret_cast<const float4*>(X + j * ND)[tid];
    __syncthreads();
    if (tid < NC) {
        const float* ci = X + 800 * ND + tid * ND;
        float s = 0.f;
        for (int d = 0; d < ND; ++d) s += ci[d] * xs[d];
        T1[tid * 1000 + j] = s;
    }
}

// P5b: T2 = Mint @ T1
__global__ void k_T2(const float* __restrict__ T1, const float* __restrict__ Mint,
                     float* __restrict__ T2) {
    __shared__ float t1s[NC * 128];
    int tid = threadIdx.x;
    int j0 = blockIdx.x * 128;
    for (int idx = tid; idx < NC * 32; idx += 128) {
        int m = idx >> 5, jq = idx & 31;
        int j = j0 + jq * 4;
        if (j < 1000) {
            float4 v = *reinterpret_cast<const float4*>(T1 + m * 1000 + j);
            *reinterpret_cast<float4*>(&t1s[m * 128 + jq * 4]) = v;
        }
    }
    __syncthreads();
    int j = j0 + tid;
    if (j < 1000) {
        for (int i = 0; i < NC; ++i) {
            float s = 0.f;
#pragma unroll 4
            for (int m = 0; m < NC; ++m) s += Mint[i * NC + m] * t1s[m * 128 + tid];
            T2[i * 1000 + j] = s;
        }
    }
}

// P6: Y[j][d] = (X[j][d] - sum_i centers[i][d]*T2[i][j]) / ridge   == A0^{-1} X_j
__global__ void k_Y(const float* __restrict__ X, const float* __restrict__ T2,
                    float* __restrict__ Y) {
    __shared__ float t2s[NC];
    int j = blockIdx.x, tid = threadIdx.x;
    for (int i = tid; i < NC; i += 256) t2s[i] = T2[i * 1000 + j];
    __syncthreads();
    const float* centers = X + 800 * ND;
    for (int d = tid; d < ND; d += 256) {
        float s = 0.f;
        for (int i = 0; i < NC; ++i) s += centers[i * ND + d] * t2s[i];
        Y[j * ND + d] = (X[j * ND + d] - s) * 10.0f;   // 1/ridge
    }
}

// P7: per class: S = D^{-1} + V^T (A0inv V); r = V^T (A0inv b); solve 9x9; W_c
__global__ void k_solve(const float* __restrict__ X, const float* __restrict__ Y,
                        float* __restrict__ W) {
    __shared__ float Vs[9 * 516];
    __shared__ float Ys[10 * 516];
    __shared__ float SL[9 * 10];
    __shared__ float zL[9];
    int c = blockIdx.x, tid = threadIdx.x;
    for (int idx = tid; idx < 9 * 128; idx += 256) {
        int a = idx >> 7, q = idx & 127;
        int row = (a < 8) ? (c * 8 + a) : (800 + c);
        reinterpret_cast<float4*>(&Vs[a * 516])[q] =
            reinterpret_cast<const float4*>(X + row * ND)[q];
    }
    for (int idx = tid; idx < 10 * 128; idx += 256) {
        int a = idx >> 7, q = idx & 127;
        int row = (a < 8) ? (c * 8 + a) : ((a == 8) ? (800 + c) : (900 + c));
        reinterpret_cast<float4*>(&Ys[a * 516])[q] =
            reinterpret_cast<const float4*>(Y + row * ND)[q];
    }
    __syncthreads();
    if (tid < 90) {
        int a = tid / 10, bb = tid - (tid / 10) * 10;
        float s = 0.f;
        for (int d = 0; d < ND; ++d) s += Vs[a * 516 + d] * Ys[bb * 516 + d];
        if (bb == a) s += 16.0f;                 // 1/ws for a<8 on diagonal
        if (bb == a && a == 8) s += -198.0f - 16.0f;  // a==8: -1/wo = -198
        SL[tid] = s;
    }
    __syncthreads();
    if (tid == 0) {
        // 9x9 Gaussian elimination with partial pivoting, rhs in col 9
        for (int p = 0; p < 9; ++p) {
            int best = p; float bv = fabsf(SL[p * 10 + p]);
            for (int r = p + 1; r < 9; ++r) {
                float v = fabsf(SL[r * 10 + p]);
                if (v > bv) { bv = v; best = r; }
            }
            if (best != p)
                for (int j = p; j < 10; ++j) {
                    float t = SL[p * 10 + j]; SL[p * 10 + j] = SL[best * 10 + j]; SL[best * 10 + j] = t;
                }
            float ip = 1.0f / SL[p * 10 + p];
            for (int r = p + 1; r < 9; ++r) {
                float f = SL[r * 10 + p] * ip;
                for (int j = p; j < 10; ++j) SL[r * 10 + j] -= f * SL[p * 10 + j];
            }
        }
        for (int p = 8; p >= 0; --p) {
            float s = SL[p * 10 + 9];
            for (int j = p + 1; j < 9; ++j) s -= SL[p * 10 + j] * zL[j];
            zL[p] = s / SL[p * 10 + p];
        }
    }
    __syncthreads();
    for (int d = tid; d < ND; d += 256) {
        float w = Ys[9 * 516 + d];
#pragma unroll
        for (int a = 0; a < 9; ++a) w -= zL[a] * Ys[a * 516 + d];
        W[c * ND + d] = w;
    }
}

// P8: rnorm[b] = 1/max(||h_b||, eps) ; one wave per row
__global__ void k_rnorm(const float* __restrict__ h, float* __restrict__ rnorm) {
    int tid = threadIdx.x;
    int wid = tid >> 6, lane = tid & 63;
    int r = blockIdx.x * 4 + wid;
    const float4* hr = reinterpret_cast<const float4*>(h + (size_t)r * ND);
    float4 v0 = hr[lane];
    float4 v1 = hr[lane + 64];
    float s = v0.x * v0.x + v0.y * v0.y + v0.z * v0.z + v0.w * v0.w
            + v1.x * v1.x + v1.y * v1.y + v1.z * v1.z + v1.w * v1.w;
    s = warpReduceSum(s);
    if (lane == 0) rnorm[r] = 1.0f / fmaxf(sqrtf(s), 1e-8f);
}

// Main: tiled GEMM [256 rows x (8 classes * 9 vecs)] with fused softmax epilogue
__global__ void k_main(const float* __restrict__ h, const float* __restrict__ X,
                       const float* __restrict__ W, const float* __restrict__ rnorm,
                       float* __restrict__ out) {
    __shared__ float As[256 * 33];
    __shared__ float Bs[72 * 36];
    int tid = threadIdx.x;
    int rg = tid & 31, cls = tid >> 5;
    int r0 = blockIdx.x * 256;
    int cb = blockIdx.y;
    int c = cb * 8 + cls;
    float acc[8][9];
#pragma unroll
    for (int i = 0; i < 8; ++i)
#pragma unroll
        for (int j = 0; j < 9; ++j) acc[i][j] = 0.f;

    for (int kc = 0; kc < 16; ++kc) {
        // stage A: 256 rows x 32 k, layout As[row][k], pitch 33 (conflict-free reads)
#pragma unroll
        for (int it = 0; it < 8; ++it) {
            int idx = tid + it * 256;
            int row = idx >> 3, kq = idx & 7;
            float4 v = reinterpret_cast<const float4*>(h + (size_t)(r0 + row) * ND + kc * 32)[kq];
            As[row * 33 + kq * 4 + 0] = v.x;
            As[row * 33 + kq * 4 + 1] = v.y;
            As[row * 33 + kq * 4 + 2] = v.z;
            As[row * 33 + kq * 4 + 3] = v.w;
        }
        // stage B: 8 classes x 9 vectors (8 Pn + W_c) x 32 k
        for (int idx = tid; idx < 576; idx += 256) {
            int vec = idx >> 3, kq = idx & 7;
            int cl = vec / 9, j = vec - cl * 9;
            int cc = cb * 8 + cl; cc = (cc < NC) ? cc : (NC - 1);
            const float* src = (j < 8) ? (X + (size_t)(cc * 8 + j) * ND) : (W + (size_t)cc * ND);
            float4 v = reinterpret_cast<const float4*>(src + kc * 32)[kq];
            Bs[vec * 36 + kq * 4 + 0] = v.x;
            Bs[vec * 36 + kq * 4 + 1] = v.y;
            Bs[vec * 36 + kq * 4 + 2] = v.z;
            Bs[vec * 36 + kq * 4 + 3] = v.w;
        }
        __syncthreads();
#pragma unroll 4
        for (int k = 0; k < 32; ++k) {
            float a[8], bv[9];
#pragma unroll
            for (int i = 0; i < 8; ++i) a[i] = As[(rg + 32 * i) * 33 + k];
#pragma unroll
            for (int j = 0; j < 9; ++j) bv[j] = Bs[(cls * 9 + j) * 36 + k];
#pragma unroll
            for (int i = 0; i < 8; ++i)
#pragma unroll
                for (int j = 0; j < 9; ++j) acc[i][j] = fmaf(a[i], bv[j], acc[i][j]);
        }
        __syncthreads();
    }

    if (c < NC) {
#pragma unroll
        for (int i = 0; i < 8; ++i) {
            int r = r0 + rg + 32 * i;
            float rn = rnorm[r];
            float cosv[8];
            float m = -1e30f;
#pragma unroll
            for (int j = 0; j < 8; ++j) { cosv[j] = acc[i][j] * rn; m = fmaxf(m, cosv[j]); }
            float se = 0.f, sec = 0.f;
#pragma unroll
            for (int j = 0; j < 8; ++j) {
                float e = __expf((cosv[j] - m) * 20.0f);   // 1/SUB_T
                se += e; sec += e * cosv[j];
            }
            float class_sim = sec / se;
            float resid = acc[i][8] * rn;
            out[(size_t)r * NC + c] = (class_sim + resid) * (1.0f / 0.07f);
        }
    }
}

extern "C" void kernel_launch(void* const* d_in, const int* in_sizes, int n_in,
                              void* d_out, int out_size, void* d_ws, size_t ws_size,
                              hipStream_t stream) {
    (void)in_sizes; (void)n_in; (void)out_size; (void)ws_size;
    const float* h = (const float*)d_in[0];
    const float* protos = (const float*)d_in[1];
    float* out = (float*)d_out;
    float* ws = (float*)d_ws;

    float* X     = ws;                 // 1000*512 = 512000  (Pn | centers | bvec)
    float* csum  = X + 512000;         // 512
    float* Ahat  = csum + 512;         // 10000
    float* Mint  = Ahat + 10000;       // 10000
    float* T1    = Mint + 10000;       // 100000
    float* T2    = T1 + 100000;        // 100000
    float* Y     = T2 + 100000;        // 512000
    float* W     = Y + 512000;         // 51200
    float* rnorm = W + 51200;          // 32768   -> total ~5.3 MB

    k_prep_class<<<NC, 256, 0, stream>>>(protos, X);
    k_csum<<<2, 256, 0, stream>>>(X, csum);
    k_bopp<<<NC, 256, 0, stream>>>(X, csum);
    k_gram<<<NC, 128, 0, stream>>>(X, Ahat);
    k_inv<<<1, 256, 0, stream>>>(Ahat, Mint);
    k_T1<<<1000, 128, 0, stream>>>(X, T1);
    k_T2<<<8, 128, 0, stream>>>(T1, Mint, T2);
    k_Y<<<1000, 256, 0, stream>>>(X, T2, Y);
    k_solve<<<NC, 256, 0, stream>>>(X, Y, W);
    k_rnorm<<<NB / 4, 256, 0, stream>>>(h, rnorm);
    dim3 grid(NB / 256, 13);
    k_main<<<grid, 256, 0, stream>>>(h, X, W, rnorm, out);
}

// Round 3
// 1004.114 us; speedup vs baseline: 3.5924x; 3.5924x over previous
//
#include <hip/hip_runtime.h>
#include <math.h>

// Problem constants
#define NB 32768
#define NC 100
#define NK 8
#define ND 512
// Pipeline:
//  prep (fp32):  Pn/centers/bvec -> Woodbury(100x100 inv) -> W [C,D]
//  k_hn:    hnb = bf16(h / max(||h||,eps))          [32768,512] bf16
//  k_packB: Bp[112*10][512] bf16: per class 8 protos, W_hi, W_lo(=W-bf16(W))
//  k_main_mfma: 128x160-tile bf16 MFMA GEMM + fused softmax epilogue

typedef __attribute__((ext_vector_type(8))) short short8;
typedef __attribute__((ext_vector_type(4))) float f32x4;

__device__ __forceinline__ float warpReduceSum(float v) {
#pragma unroll
    for (int off = 32; off > 0; off >>= 1) v += __shfl_xor(v, off);
    return v;
}

__device__ float blockReduceSum256(float v, float* red) {
    int tid = threadIdx.x;
    v = warpReduceSum(v);
    __syncthreads();
    if ((tid & 63) == 0) red[tid >> 6] = v;
    __syncthreads();
    return red[0] + red[1] + red[2] + red[3];
}

__device__ __forceinline__ unsigned short f2bf(float x) {
    unsigned u = __float_as_uint(x);
    u = (u + 0x7FFFu + ((u >> 16) & 1u)) >> 16;
    return (unsigned short)u;
}
__device__ __forceinline__ float bf2f(unsigned short h) {
    return __uint_as_float(((unsigned)h) << 16);
}

// ------------------------- prep kernels (fp32) -------------------------

__global__ void k_prep_class(const float* __restrict__ protos, float* __restrict__ X) {
    __shared__ float red[4];
    int c = blockIdx.x;
    int tid = threadIdx.x;
    const float eps = 1e-8f;
    float pv0[NK], pv1[NK];
#pragma unroll
    for (int k = 0; k < NK; ++k) {
        pv0[k] = protos[(c * NK + k) * ND + tid];
        pv1[k] = protos[(c * NK + k) * ND + tid + 256];
    }
    float sv0 = 0.f, sv1 = 0.f;
#pragma unroll
    for (int k = 0; k < NK; ++k) {
        float ss = blockReduceSum256(pv0[k] * pv0[k] + pv1[k] * pv1[k], red);
        float inv = 1.0f / fmaxf(sqrtf(ss), eps);
        pv0[k] *= inv; pv1[k] *= inv;
        X[(c * NK + k) * ND + tid] = pv0[k];
        X[(c * NK + k) * ND + tid + 256] = pv1[k];
        sv0 += pv0[k]; sv1 += pv1[k];
    }
    float ssum = blockReduceSum256(sv0 * sv0 + sv1 * sv1, red);
    float mnorm = sqrtf(ssum) * 0.125f;
    float cinv = 0.125f / fmaxf(mnorm, eps);
    float* centers = X + 800 * ND;
    centers[c * ND + tid] = sv0 * cinv;
    centers[c * ND + tid + 256] = sv1 * cinv;
    const float ws = 0.5f / 8.0f;
    float* bvec = X + 900 * ND;
    bvec[c * ND + tid] = ws * sv0;
    bvec[c * ND + tid + 256] = ws * sv1;
}

__global__ void k_csum(const float* __restrict__ X, float* __restrict__ csum) {
    int d = blockIdx.x * blockDim.x + threadIdx.x;
    const float* centers = X + 800 * ND;
    float s = 0.f;
    for (int c = 0; c < NC; ++c) s += centers[c * ND + d];
    csum[d] = s;
}

__global__ void k_bopp(float* __restrict__ X, const float* __restrict__ csum) {
    int c = blockIdx.x, tid = threadIdx.x;
    const float wo = 0.5f / 99.0f;
    const float* centers = X + 800 * ND;
    float* bvec = X + 900 * ND;
    for (int d = tid; d < ND; d += 256)
        bvec[c * ND + d] -= wo * (csum[d] - centers[c * ND + d]);
}

__global__ void k_gram(const float* __restrict__ X, float* __restrict__ Ahat) {
    __shared__ float cs[ND];
    int i = blockIdx.x, tid = threadIdx.x;
    const float* centers = X + 800 * ND;
    for (int d = tid; d < ND; d += 128) cs[d] = centers[i * ND + d];
    __syncthreads();
    if (tid < NC) {
        const float* cj = centers + tid * ND;
        float s = 0.f;
        for (int d = 0; d < ND; ++d) s += cs[d] * cj[d];
        if (tid == i) s += 0.1f * 99.0f / 0.5f;  // ridge/wo = 19.8
        Ahat[i * NC + tid] = s;
    }
}

__global__ void k_inv(const float* __restrict__ Ahat, float* __restrict__ Mint) {
    __shared__ float A[NC * NC];
    __shared__ float prow[NC];
    __shared__ float fcol[NC];
    int tid = threadIdx.x;
    for (int idx = tid; idx < NC * NC; idx += 256) A[idx] = Ahat[idx];
    __syncthreads();
    for (int p = 0; p < NC; ++p) {
        float ipiv = 1.0f / A[p * NC + p];
        for (int j = tid; j < NC; j += 256) prow[j] = (j == p) ? ipiv : A[p * NC + j] * ipiv;
        for (int r = tid; r < NC; r += 256) fcol[r] = A[r * NC + p];
        __syncthreads();
        for (int idx = tid; idx < NC * NC; idx += 256) {
            int r = idx / NC, j = idx - r * NC;
            float pr = prow[j];
            A[idx] = (r == p) ? pr : ((j == p) ? (-fcol[r] * ipiv) : (A[idx] - fcol[r] * pr));
        }
        __syncthreads();
    }
    for (int idx = tid; idx < NC * NC; idx += 256) Mint[idx] = A[idx];
}

__global__ void k_T1(const float* __restrict__ X, float* __restrict__ T1) {
    __shared__ float xs[ND];
    int j = blockIdx.x, tid = threadIdx.x;
    reinterpret_cast<float4*>(xs)[tid] = reinterpret_cast<const float4*>(X + j * ND)[tid];
    __syncthreads();
    if (tid < NC) {
        const float* ci = X + 800 * ND + tid * ND;
        float s = 0.f;
        for (int d = 0; d < ND; ++d) s += ci[d] * xs[d];
        T1[tid * 1000 + j] = s;
    }
}

__global__ void k_T2(const float* __restrict__ T1, const float* __restrict__ Mint,
                     float* __restrict__ T2) {
    __shared__ float t1s[NC * 128];
    int tid = threadIdx.x;
    int j0 = blockIdx.x * 128;
    for (int idx = tid; idx < NC * 32; idx += 128) {
        int m = idx >> 5, jq = idx & 31;
        int j = j0 + jq * 4;
        if (j < 1000) {
            float4 v = *reinterpret_cast<const float4*>(T1 + m * 1000 + j);
            *reinterpret_cast<float4*>(&t1s[m * 128 + jq * 4]) = v;
        }
    }
    __syncthreads();
    int j = j0 + tid;
    if (j < 1000) {
        for (int i = 0; i < NC; ++i) {
            float s = 0.f;
#pragma unroll 4
            for (int m = 0; m < NC; ++m) s += Mint[i * NC + m] * t1s[m * 128 + tid];
            T2[i * 1000 + j] = s;
        }
    }
}

__global__ void k_Y(const float* __restrict__ X, const float* __restrict__ T2,
                    float* __restrict__ Y) {
    __shared__ float t2s[NC];
    int j = blockIdx.x, tid = threadIdx.x;
    for (int i = tid; i < NC; i += 256) t2s[i] = T2[i * 1000 + j];
    __syncthreads();
    const float* centers = X + 800 * ND;
    for (int d = tid; d < ND; d += 256) {
        float s = 0.f;
        for (int i = 0; i < NC; ++i) s += centers[i * ND + d] * t2s[i];
        Y[j * ND + d] = (X[j * ND + d] - s) * 10.0f;
    }
}

__global__ void k_solve(const float* __restrict__ X, const float* __restrict__ Y,
                        float* __restrict__ W) {
    __shared__ float Vs[9 * 516];
    __shared__ float Ys[10 * 516];
    __shared__ float SL[9 * 10];
    __shared__ float zL[9];
    int c = blockIdx.x, tid = threadIdx.x;
    for (int idx = tid; idx < 9 * 128; idx += 256) {
        int a = idx >> 7, q = idx & 127;
        int row = (a < 8) ? (c * 8 + a) : (800 + c);
        reinterpret_cast<float4*>(&Vs[a * 516])[q] =
            reinterpret_cast<const float4*>(X + row * ND)[q];
    }
    for (int idx = tid; idx < 10 * 128; idx += 256) {
        int a = idx >> 7, q = idx & 127;
        int row = (a < 8) ? (c * 8 + a) : ((a == 8) ? (800 + c) : (900 + c));
        reinterpret_cast<float4*>(&Ys[a * 516])[q] =
            reinterpret_cast<const float4*>(Y + row * ND)[q];
    }
    __syncthreads();
    if (tid < 90) {
        int a = tid / 10, bb = tid - (tid / 10) * 10;
        float s = 0.f;
        for (int d = 0; d < ND; ++d) s += Vs[a * 516 + d] * Ys[bb * 516 + d];
        if (bb == a) s += 16.0f;
        if (bb == a && a == 8) s += -198.0f - 16.0f;
        SL[tid] = s;
    }
    __syncthreads();
    if (tid == 0) {
        for (int p = 0; p < 9; ++p) {
            int best = p; float bv = fabsf(SL[p * 10 + p]);
            for (int r = p + 1; r < 9; ++r) {
                float v = fabsf(SL[r * 10 + p]);
                if (v > bv) { bv = v; best = r; }
            }
            if (best != p)
                for (int j = p; j < 10; ++j) {
                    float t = SL[p * 10 + j]; SL[p * 10 + j] = SL[best * 10 + j]; SL[best * 10 + j] = t;
                }
            float ip = 1.0f / SL[p * 10 + p];
            for (int r = p + 1; r < 9; ++r) {
                float f = SL[r * 10 + p] * ip;
                for (int j = p; j < 10; ++j) SL[r * 10 + j] -= f * SL[p * 10 + j];
            }
        }
        for (int p = 8; p >= 0; --p) {
            float s = SL[p * 10 + 9];
            for (int j = p + 1; j < 9; ++j) s -= SL[p * 10 + j] * zL[j];
            zL[p] = s / SL[p * 10 + p];
        }
    }
    __syncthreads();
    for (int d = tid; d < ND; d += 256) {
        float w = Ys[9 * 516 + d];
#pragma unroll
        for (int a = 0; a < 9; ++a) w -= zL[a] * Ys[a * 516 + d];
        W[c * ND + d] = w;
    }
}

// ------------------------- bf16 packing -------------------------

// hnb[b][d] = bf16(h[b]/max(||h_b||,eps));  one wave per row
__global__ void k_hn(const float* __restrict__ h, unsigned short* __restrict__ hnb) {
    int tid = threadIdx.x;
    int wave = tid >> 6, lane = tid & 63;
    int r = blockIdx.x * 4 + wave;
    const float4* hp = reinterpret_cast<const float4*>(h + (size_t)r * ND);
    float4 v0 = hp[lane * 2];
    float4 v1 = hp[lane * 2 + 1];
    float s = v0.x * v0.x + v0.y * v0.y + v0.z * v0.z + v0.w * v0.w
            + v1.x * v1.x + v1.y * v1.y + v1.z * v1.z + v1.w * v1.w;
    s = warpReduceSum(s);
    float inv = 1.0f / fmaxf(sqrtf(s), 1e-8f);
    uint4 o;
    o.x = (unsigned)f2bf(v0.x * inv) | ((unsigned)f2bf(v0.y * inv) << 16);
    o.y = (unsigned)f2bf(v0.z * inv) | ((unsigned)f2bf(v0.w * inv) << 16);
    o.z = (unsigned)f2bf(v1.x * inv) | ((unsigned)f2bf(v1.y * inv) << 16);
    o.w = (unsigned)f2bf(v1.z * inv) | ((unsigned)f2bf(v1.w * inv) << 16);
    reinterpret_cast<uint4*>(hnb + (size_t)r * ND)[lane] = o;
}

// Bp: 1120 rows (112 class-slots x 10): j<8 -> Pn, j==8 -> bf16(W), j==9 -> bf16(W - bf16(W))
__global__ void k_packB(const float* __restrict__ X, const float* __restrict__ W,
                        unsigned short* __restrict__ Bp) {
    int tid = threadIdx.x;
    int row = blockIdx.x * 4 + (tid >> 6);
    int lane = tid & 63;
    int c = row / 10, j = row - c * 10;
    float vals[8];
    if (c >= NC) {
#pragma unroll
        for (int q = 0; q < 8; ++q) vals[q] = 0.f;
    } else if (j < 8) {
        const float* src = X + (size_t)(c * 8 + j) * ND + lane * 8;
#pragma unroll
        for (int q = 0; q < 8; ++q) vals[q] = src[q];
    } else {
        const float* src = W + (size_t)c * ND + lane * 8;
#pragma unroll
        for (int q = 0; q < 8; ++q) {
            float w = src[q];
            vals[q] = (j == 8) ? w : (w - bf2f(f2bf(w)));
        }
    }
    uint4 o;
    o.x = (unsigned)f2bf(vals[0]) | ((unsigned)f2bf(vals[1]) << 16);
    o.y = (unsigned)f2bf(vals[2]) | ((unsigned)f2bf(vals[3]) << 16);
    o.z = (unsigned)f2bf(vals[4]) | ((unsigned)f2bf(vals[5]) << 16);
    o.w = (unsigned)f2bf(vals[6]) | ((unsigned)f2bf(vals[7]) << 16);
    reinterpret_cast<uint4*>(Bp + (size_t)row * ND)[lane] = o;
}

// ------------------------- main MFMA GEMM + fused epilogue -------------------------
// Block: 128 rows x 160 cols (16 class-slots). 4 waves, each 4 row-tiles x 5 col-tiles
// of 16x16x32 bf16 MFMA. LDS: union{ As[128][72] bf16, Bs[160][72] bf16 | Cs[64][162] f32 }.

__global__ __launch_bounds__(256, 2) void k_main_mfma(
        const unsigned short* __restrict__ hnb, const unsigned short* __restrict__ Bp,
        float* __restrict__ out) {
    __shared__ __align__(16) char smem[41472];
    unsigned short* As = (unsigned short*)smem;          // 128*72 shorts = 18432 B
    unsigned short* Bs = (unsigned short*)smem + 9216;   // 160*72 shorts = 23040 B
    float* Cs = (float*)smem;                            // 64*162 floats = 41472 B

    int tid = threadIdx.x;
    int wave = tid >> 6, lane = tid & 63;
    int m = lane & 15, g = lane >> 4;
    int rowhalf = wave & 1, colhalf = wave >> 1;
    int cb = blockIdx.x;          // 0..6  (col block: 16 class-slots)
    int r0 = blockIdx.y * 128;    // row block

    f32x4 acc[4][5] = {};

    for (int kc = 0; kc < 8; ++kc) {
        __syncthreads();
        // stage A: 128 rows x 64 k; each thread copies 32 bf16 (64 B)
        {
            int row = tid >> 1, half = tid & 1;
            const uint4* src = reinterpret_cast<const uint4*>(
                hnb + (size_t)(r0 + row) * ND + kc * 64 + half * 32);
            uint4* dst = reinterpret_cast<uint4*>(As + row * 72 + half * 32);
            dst[0] = src[0]; dst[1] = src[1]; dst[2] = src[2]; dst[3] = src[3];
        }
        // stage B: 160 rows x 64 k; 320 half-row copies of 32 bf16 (64 B)
        for (int idx = tid; idx < 320; idx += 256) {
            int brow = idx >> 1, half = idx & 1;
            int gcol = cb * 160 + brow;
            const uint4* src = reinterpret_cast<const uint4*>(
                Bp + (size_t)gcol * ND + kc * 64 + half * 32);
            uint4* dst = reinterpret_cast<uint4*>(Bs + brow * 72 + half * 32);
            dst[0] = src[0]; dst[1] = src[1]; dst[2] = src[2]; dst[3] = src[3];
        }
        __syncthreads();
#pragma unroll
        for (int kk = 0; kk < 2; ++kk) {
            short8 af[4], bfr[5];
#pragma unroll
            for (int rt = 0; rt < 4; ++rt)
                af[rt] = *reinterpret_cast<const short8*>(
                    As + (rowhalf * 64 + rt * 16 + m) * 72 + kk * 32 + g * 8);
#pragma unroll
            for (int ct = 0; ct < 5; ++ct)
                bfr[ct] = *reinterpret_cast<const short8*>(
                    Bs + (colhalf * 80 + ct * 16 + m) * 72 + kk * 32 + g * 8);
#pragma unroll
            for (int rt = 0; rt < 4; ++rt)
#pragma unroll
                for (int ct = 0; ct < 5; ++ct)
                    acc[rt][ct] = __builtin_amdgcn_mfma_f32_16x16x32_bf16(
                        af[rt], bfr[ct], acc[rt][ct], 0, 0, 0);
        }
    }

    // fused epilogue: two 64-row passes through LDS (C/D layout: col=lane&15, row=g*4+reg)
    for (int p = 0; p < 2; ++p) {
        __syncthreads();
        if (rowhalf == p) {
#pragma unroll
            for (int rt = 0; rt < 4; ++rt)
#pragma unroll
                for (int ct = 0; ct < 5; ++ct)
#pragma unroll
                    for (int reg = 0; reg < 4; ++reg) {
                        int lr = rt * 16 + g * 4 + reg;
                        int lc = colhalf * 80 + ct * 16 + m;
                        Cs[lr * 162 + lc] = acc[rt][ct][reg];
                    }
        }
        __syncthreads();
        {
            int cl = tid & 15;
            int c = cb * 16 + cl;
#pragma unroll
            for (int q = 0; q < 4; ++q) {
                int r = (tid >> 4) + q * 16;
                float v[10];
#pragma unroll
                for (int j = 0; j < 10; ++j) v[j] = Cs[r * 162 + cl * 10 + j];
                float mx = v[0];
#pragma unroll
                for (int j = 1; j < 8; ++j) mx = fmaxf(mx, v[j]);
                float se = 0.f, sec = 0.f;
#pragma unroll
                for (int j = 0; j < 8; ++j) {
                    float e = __expf((v[j] - mx) * 20.0f);  // 1/SUB_T
                    se += e; sec += e * v[j];
                }
                float res = v[8] + v[9];
                if (c < NC)
                    out[(size_t)(r0 + p * 64 + r) * NC + c] =
                        (sec / se + res) * (1.0f / 0.07f);
            }
        }
    }
}

extern "C" void kernel_launch(void* const* d_in, const int* in_sizes, int n_in,
                              void* d_out, int out_size, void* d_ws, size_t ws_size,
                              hipStream_t stream) {
    (void)in_sizes; (void)n_in; (void)out_size; (void)ws_size;
    const float* h = (const float*)d_in[0];
    const float* protos = (const float*)d_in[1];
    float* out = (float*)d_out;
    float* ws = (float*)d_ws;

    float* X    = ws;                  // 512000  (Pn | centers | bvec)
    float* csum = X + 512000;          // 512
    float* Ahat = csum + 512;          // 10000
    float* Mint = Ahat + 10000;        // 10000
    float* T1   = Mint + 10000;        // 100000
    float* T2   = T1 + 100000;         // 100000
    float* Y    = T2 + 100000;         // 512000
    float* W    = Y + 512000;          // 51200
    unsigned short* hnb = (unsigned short*)(W + 51200);   // 32768*512 bf16 = 33.5 MB
    unsigned short* Bp  = hnb + (size_t)NB * ND;          // 1120*512 bf16 = 1.15 MB

    k_hn<<<NB / 4, 256, 0, stream>>>(h, hnb);
    k_prep_class<<<NC, 256, 0, stream>>>(protos, X);
    k_csum<<<2, 256, 0, stream>>>(X, csum);
    k_bopp<<<NC, 256, 0, stream>>>(X, csum);
    k_gram<<<NC, 128, 0, stream>>>(X, Ahat);
    k_inv<<<1, 256, 0, stream>>>(Ahat, Mint);
    k_T1<<<1000, 128, 0, stream>>>(X, T1);
    k_T2<<<8, 128, 0, stream>>>(T1, Mint, T2);
    k_Y<<<1000, 256, 0, stream>>>(X, T2, Y);
    k_solve<<<NC, 256, 0, stream>>>(X, Y, W);
    k_packB<<<280, 256, 0, stream>>>(X, W, Bp);
    dim3 grid(7, NB / 128);
    k_main_mfma<<<grid, 256, 0, stream>>>(hnb, Bp, out);
}

// Round 4
// 275.190 us; speedup vs baseline: 13.1081x; 3.6488x over previous
//
#include <hip/hip_runtime.h>
#include <math.h>

// Problem constants
#define NB 32768
#define NC 100
#define NK 8
#define ND 512
#define ALPHA 22.0f      // Neumann split: Ahat = ALPHA*(I - M); eig(Ahat) in [19.8, ~24.3]
#define NEU_ITERS 12
// Pipeline:
//  prep (fp32):  Pn/centers/bvec -> Woodbury via Neumann series -> W [C,D]
//  k_hn:    hnb = bf16(h / max(||h||,eps))          [32768,512] bf16
//  k_packB: Bp[112*10][512] bf16: per class 8 protos, W_hi, W_lo(=W-bf16(W))
//  k_main_mfma: 128x160-tile bf16 MFMA GEMM + fused softmax epilogue

typedef __attribute__((ext_vector_type(8))) short short8;
typedef __attribute__((ext_vector_type(4))) float f32x4;

__device__ __forceinline__ float warpReduceSum(float v) {
#pragma unroll
    for (int off = 32; off > 0; off >>= 1) v += __shfl_xor(v, off);
    return v;
}

__device__ float blockReduceSum256(float v, float* red) {
    int tid = threadIdx.x;
    v = warpReduceSum(v);
    __syncthreads();
    if ((tid & 63) == 0) red[tid >> 6] = v;
    __syncthreads();
    return red[0] + red[1] + red[2] + red[3];
}

__device__ __forceinline__ unsigned short f2bf(float x) {
    unsigned u = __float_as_uint(x);
    u = (u + 0x7FFFu + ((u >> 16) & 1u)) >> 16;
    return (unsigned short)u;
}
__device__ __forceinline__ float bf2f(unsigned short h) {
    return __uint_as_float(((unsigned)h) << 16);
}

// ------------------------- prep kernels (fp32) -------------------------

__global__ void k_prep_class(const float* __restrict__ protos, float* __restrict__ X) {
    __shared__ float red[4];
    int c = blockIdx.x;
    int tid = threadIdx.x;
    const float eps = 1e-8f;
    float pv0[NK], pv1[NK];
#pragma unroll
    for (int k = 0; k < NK; ++k) {
        pv0[k] = protos[(c * NK + k) * ND + tid];
        pv1[k] = protos[(c * NK + k) * ND + tid + 256];
    }
    float sv0 = 0.f, sv1 = 0.f;
#pragma unroll
    for (int k = 0; k < NK; ++k) {
        float ss = blockReduceSum256(pv0[k] * pv0[k] + pv1[k] * pv1[k], red);
        float inv = 1.0f / fmaxf(sqrtf(ss), eps);
        pv0[k] *= inv; pv1[k] *= inv;
        X[(c * NK + k) * ND + tid] = pv0[k];
        X[(c * NK + k) * ND + tid + 256] = pv1[k];
        sv0 += pv0[k]; sv1 += pv1[k];
    }
    float ssum = blockReduceSum256(sv0 * sv0 + sv1 * sv1, red);
    float mnorm = sqrtf(ssum) * 0.125f;
    float cinv = 0.125f / fmaxf(mnorm, eps);
    float* centers = X + 800 * ND;
    centers[c * ND + tid] = sv0 * cinv;
    centers[c * ND + tid + 256] = sv1 * cinv;
    const float ws = 0.5f / 8.0f;
    float* bvec = X + 900 * ND;
    bvec[c * ND + tid] = ws * sv0;
    bvec[c * ND + tid + 256] = ws * sv1;
}

__global__ void k_csum(const float* __restrict__ X, float* __restrict__ csum) {
    int d = blockIdx.x * blockDim.x + threadIdx.x;
    const float* centers = X + 800 * ND;
    float s = 0.f;
    for (int c = 0; c < NC; ++c) s += centers[c * ND + d];
    csum[d] = s;
}

__global__ void k_bopp(float* __restrict__ X, const float* __restrict__ csum) {
    int c = blockIdx.x, tid = threadIdx.x;
    const float wo = 0.5f / 99.0f;
    const float* centers = X + 800 * ND;
    float* bvec = X + 900 * ND;
    for (int d = tid; d < ND; d += 256)
        bvec[c * ND + d] -= wo * (csum[d] - centers[c * ND + d]);
}

// M = I - Ahat/ALPHA, Ahat = (ridge/wo) I + C C^T  (100x100)
__global__ void k_gram(const float* __restrict__ X, float* __restrict__ M) {
    __shared__ float cs[ND];
    int i = blockIdx.x, tid = threadIdx.x;
    const float* centers = X + 800 * ND;
    for (int d = tid; d < ND; d += 128) cs[d] = centers[i * ND + d];
    __syncthreads();
    if (tid < NC) {
        const float* cj = centers + tid * ND;
        float s = 0.f;
        for (int d = 0; d < ND; ++d) s += cs[d] * cj[d];
        float ahat = s + ((tid == i) ? (0.1f * 99.0f / 0.5f) : 0.f);  // +19.8 on diag
        M[i * NC + tid] = ((tid == i) ? 1.f : 0.f) - ahat * (1.0f / ALPHA);
    }
}

// T1[j][i] = centers_i . X_j   (layout [1000][100], coalesced write)
__global__ void k_T1(const float* __restrict__ X, float* __restrict__ T1) {
    __shared__ float xs[ND];
    int j = blockIdx.x, tid = threadIdx.x;
    reinterpret_cast<float4*>(xs)[tid] = reinterpret_cast<const float4*>(X + j * ND)[tid];
    __syncthreads();
    if (tid < NC) {
        const float* ci = X + 800 * ND + tid * ND;
        float s = 0.f;
        for (int d = 0; d < ND; ++d) s += ci[d] * xs[d];
        T1[j * NC + tid] = s;
    }
}

// T2[j][:] = Ahat^{-1} T1[j][:] via Neumann: (1/ALPHA) * sum_{k=0}^{K} M^k t1
// 4 waves/block, one column per wave; M in LDS (stride 108: 16B-aligned, conflict-free)
__global__ __launch_bounds__(256) void k_T2neu(const float* __restrict__ M,
                                               const float* __restrict__ T1,
                                               float* __restrict__ T2) {
    __shared__ float Msh[NC * 108];      // 43.2 KB
    __shared__ float pbuf[2][4][104];    // 3.3 KB, wave-private double buffer
    int tid = threadIdx.x;
    int wave = tid >> 6, lane = tid & 63;
    int j = blockIdx.x * 4 + wave;       // 0..999
    for (int idx = tid; idx < NC * NC; idx += 256) {
        int i = idx / NC, m = idx - i * NC;
        Msh[i * 108 + m] = M[idx];
    }
    int i0 = lane;
    int i1 = lane + 64;
    int i1c = (i1 < NC) ? i1 : 0;        // clamped for in-bounds reads
    float t0 = T1[j * NC + i0];
    float t1v = (i1 < NC) ? T1[j * NC + i1] : 0.f;
    float s0 = t0, s1 = t1v;
    pbuf[0][wave][i0] = t0;
    if (i1 < NC) pbuf[0][wave][i1] = t1v;
    __syncthreads();
    int cur = 0;
    for (int it = 0; it < NEU_ITERS; ++it) {
        const float* p = pbuf[cur][wave];
        float y0 = 0.f, y1 = 0.f;
#pragma unroll 5
        for (int m = 0; m < NC; m += 4) {
            float4 pv = *reinterpret_cast<const float4*>(p + m);
            float4 a0 = *reinterpret_cast<const float4*>(&Msh[i0 * 108 + m]);
            float4 a1 = *reinterpret_cast<const float4*>(&Msh[i1c * 108 + m]);
            y0 = fmaf(a0.x, pv.x, y0); y0 = fmaf(a0.y, pv.y, y0);
            y0 = fmaf(a0.z, pv.z, y0); y0 = fmaf(a0.w, pv.w, y0);
            y1 = fmaf(a1.x, pv.x, y1); y1 = fmaf(a1.y, pv.y, y1);
            y1 = fmaf(a1.z, pv.z, y1); y1 = fmaf(a1.w, pv.w, y1);
        }
        s0 += y0; s1 += y1;
        int nxt = cur ^ 1;
        pbuf[nxt][wave][i0] = y0;
        if (i1 < NC) pbuf[nxt][wave][i1] = y1;
        cur = nxt;
    }
    T2[j * NC + i0] = s0 * (1.0f / ALPHA);
    if (i1 < NC) T2[j * NC + i1] = s1 * (1.0f / ALPHA);
}

// Y[j][d] = (X[j][d] - sum_i centers[i][d]*T2[j][i]) / ridge   == A0^{-1} X_j
__global__ void k_Y(const float* __restrict__ X, const float* __restrict__ T2,
                    float* __restrict__ Y) {
    __shared__ float t2s[NC];
    int j = blockIdx.x, tid = threadIdx.x;
    for (int i = tid; i < NC; i += 256) t2s[i] = T2[j * NC + i];
    __syncthreads();
    const float* centers = X + 800 * ND;
    for (int d = tid; d < ND; d += 256) {
        float s = 0.f;
        for (int i = 0; i < NC; ++i) s += centers[i * ND + d] * t2s[i];
        Y[j * ND + d] = (X[j * ND + d] - s) * 10.0f;
    }
}

__global__ void k_solve(const float* __restrict__ X, const float* __restrict__ Y,
                        float* __restrict__ W) {
    __shared__ float Vs[9 * 516];
    __shared__ float Ys[10 * 516];
    __shared__ float SL[9 * 10];
    __shared__ float zL[9];
    int c = blockIdx.x, tid = threadIdx.x;
    for (int idx = tid; idx < 9 * 128; idx += 256) {
        int a = idx >> 7, q = idx & 127;
        int row = (a < 8) ? (c * 8 + a) : (800 + c);
        reinterpret_cast<float4*>(&Vs[a * 516])[q] =
            reinterpret_cast<const float4*>(X + row * ND)[q];
    }
    for (int idx = tid; idx < 10 * 128; idx += 256) {
        int a = idx >> 7, q = idx & 127;
        int row = (a < 8) ? (c * 8 + a) : ((a == 8) ? (800 + c) : (900 + c));
        reinterpret_cast<float4*>(&Ys[a * 516])[q] =
            reinterpret_cast<const float4*>(Y + row * ND)[q];
    }
    __syncthreads();
    if (tid < 90) {
        int a = tid / 10, bb = tid - (tid / 10) * 10;
        float s = 0.f;
        for (int d = 0; d < ND; ++d) s += Vs[a * 516 + d] * Ys[bb * 516 + d];
        if (bb == a) s += 16.0f;
        if (bb == a && a == 8) s += -198.0f - 16.0f;
        SL[tid] = s;
    }
    __syncthreads();
    if (tid == 0) {
        for (int p = 0; p < 9; ++p) {
            int best = p; float bv = fabsf(SL[p * 10 + p]);
            for (int r = p + 1; r < 9; ++r) {
                float v = fabsf(SL[r * 10 + p]);
                if (v > bv) { bv = v; best = r; }
            }
            if (best != p)
                for (int j = p; j < 10; ++j) {
                    float t = SL[p * 10 + j]; SL[p * 10 + j] = SL[best * 10 + j]; SL[best * 10 + j] = t;
                }
            float ip = 1.0f / SL[p * 10 + p];
            for (int r = p + 1; r < 9; ++r) {
                float f = SL[r * 10 + p] * ip;
                for (int j = p; j < 10; ++j) SL[r * 10 + j] -= f * SL[p * 10 + j];
            }
        }
        for (int p = 8; p >= 0; --p) {
            float s = SL[p * 10 + 9];
            for (int j = p + 1; j < 9; ++j) s -= SL[p * 10 + j] * zL[j];
            zL[p] = s / SL[p * 10 + p];
        }
    }
    __syncthreads();
    for (int d = tid; d < ND; d += 256) {
        float w = Ys[9 * 516 + d];
#pragma unroll
        for (int a = 0; a < 9; ++a) w -= zL[a] * Ys[a * 516 + d];
        W[c * ND + d] = w;
    }
}

// ------------------------- bf16 packing -------------------------

__global__ void k_hn(const float* __restrict__ h, unsigned short* __restrict__ hnb) {
    int tid = threadIdx.x;
    int wave = tid >> 6, lane = tid & 63;
    int r = blockIdx.x * 4 + wave;
    const float4* hp = reinterpret_cast<const float4*>(h + (size_t)r * ND);
    float4 v0 = hp[lane * 2];
    float4 v1 = hp[lane * 2 + 1];
    float s = v0.x * v0.x + v0.y * v0.y + v0.z * v0.z + v0.w * v0.w
            + v1.x * v1.x + v1.y * v1.y + v1.z * v1.z + v1.w * v1.w;
    s = warpReduceSum(s);
    float inv = 1.0f / fmaxf(sqrtf(s), 1e-8f);
    uint4 o;
    o.x = (unsigned)f2bf(v0.x * inv) | ((unsigned)f2bf(v0.y * inv) << 16);
    o.y = (unsigned)f2bf(v0.z * inv) | ((unsigned)f2bf(v0.w * inv) << 16);
    o.z = (unsigned)f2bf(v1.x * inv) | ((unsigned)f2bf(v1.y * inv) << 16);
    o.w = (unsigned)f2bf(v1.z * inv) | ((unsigned)f2bf(v1.w * inv) << 16);
    reinterpret_cast<uint4*>(hnb + (size_t)r * ND)[lane] = o;
}

__global__ void k_packB(const float* __restrict__ X, const float* __restrict__ W,
                        unsigned short* __restrict__ Bp) {
    int tid = threadIdx.x;
    int row = blockIdx.x * 4 + (tid >> 6);
    int lane = tid & 63;
    int c = row / 10, j = row - c * 10;
    float vals[8];
    if (c >= NC) {
#pragma unroll
        for (int q = 0; q < 8; ++q) vals[q] = 0.f;
    } else if (j < 8) {
        const float* src = X + (size_t)(c * 8 + j) * ND + lane * 8;
#pragma unroll
        for (int q = 0; q < 8; ++q) vals[q] = src[q];
    } else {
        const float* src = W + (size_t)c * ND + lane * 8;
#pragma unroll
        for (int q = 0; q < 8; ++q) {
            float w = src[q];
            vals[q] = (j == 8) ? w : (w - bf2f(f2bf(w)));
        }
    }
    uint4 o;
    o.x = (unsigned)f2bf(vals[0]) | ((unsigned)f2bf(vals[1]) << 16);
    o.y = (unsigned)f2bf(vals[2]) | ((unsigned)f2bf(vals[3]) << 16);
    o.z = (unsigned)f2bf(vals[4]) | ((unsigned)f2bf(vals[5]) << 16);
    o.w = (unsigned)f2bf(vals[6]) | ((unsigned)f2bf(vals[7]) << 16);
    reinterpret_cast<uint4*>(Bp + (size_t)row * ND)[lane] = o;
}

// ------------------------- main MFMA GEMM + fused epilogue -------------------------

__global__ __launch_bounds__(256, 2) void k_main_mfma(
        const unsigned short* __restrict__ hnb, const unsigned short* __restrict__ Bp,
        float* __restrict__ out) {
    __shared__ __align__(16) char smem[41472];
    unsigned short* As = (unsigned short*)smem;          // 128*72 shorts
    unsigned short* Bs = (unsigned short*)smem + 9216;   // 160*72 shorts
    float* Cs = (float*)smem;                            // 64*162 floats

    int tid = threadIdx.x;
    int wave = tid >> 6, lane = tid & 63;
    int m = lane & 15, g = lane >> 4;
    int rowhalf = wave & 1, colhalf = wave >> 1;
    int cb = blockIdx.x;
    int r0 = blockIdx.y * 128;

    f32x4 acc[4][5] = {};

    for (int kc = 0; kc < 8; ++kc) {
        __syncthreads();
        {
            int row = tid >> 1, half = tid & 1;
            const uint4* src = reinterpret_cast<const uint4*>(
                hnb + (size_t)(r0 + row) * ND + kc * 64 + half * 32);
            uint4* dst = reinterpret_cast<uint4*>(As + row * 72 + half * 32);
            dst[0] = src[0]; dst[1] = src[1]; dst[2] = src[2]; dst[3] = src[3];
        }
        for (int idx = tid; idx < 320; idx += 256) {
            int brow = idx >> 1, half = idx & 1;
            int gcol = cb * 160 + brow;
            const uint4* src = reinterpret_cast<const uint4*>(
                Bp + (size_t)gcol * ND + kc * 64 + half * 32);
            uint4* dst = reinterpret_cast<uint4*>(Bs + brow * 72 + half * 32);
            dst[0] = src[0]; dst[1] = src[1]; dst[2] = src[2]; dst[3] = src[3];
        }
        __syncthreads();
#pragma unroll
        for (int kk = 0; kk < 2; ++kk) {
            short8 af[4], bfr[5];
#pragma unroll
            for (int rt = 0; rt < 4; ++rt)
                af[rt] = *reinterpret_cast<const short8*>(
                    As + (rowhalf * 64 + rt * 16 + m) * 72 + kk * 32 + g * 8);
#pragma unroll
            for (int ct = 0; ct < 5; ++ct)
                bfr[ct] = *reinterpret_cast<const short8*>(
                    Bs + (colhalf * 80 + ct * 16 + m) * 72 + kk * 32 + g * 8);
#pragma unroll
            for (int rt = 0; rt < 4; ++rt)
#pragma unroll
                for (int ct = 0; ct < 5; ++ct)
                    acc[rt][ct] = __builtin_amdgcn_mfma_f32_16x16x32_bf16(
                        af[rt], bfr[ct], acc[rt][ct], 0, 0, 0);
        }
    }

    for (int p = 0; p < 2; ++p) {
        __syncthreads();
        if (rowhalf == p) {
#pragma unroll
            for (int rt = 0; rt < 4; ++rt)
#pragma unroll
                for (int ct = 0; ct < 5; ++ct)
#pragma unroll
                    for (int reg = 0; reg < 4; ++reg) {
                        int lr = rt * 16 + g * 4 + reg;
                        int lc = colhalf * 80 + ct * 16 + m;
                        Cs[lr * 162 + lc] = acc[rt][ct][reg];
                    }
        }
        __syncthreads();
        {
            int cl = tid & 15;
            int c = cb * 16 + cl;
#pragma unroll
            for (int q = 0; q < 4; ++q) {
                int r = (tid >> 4) + q * 16;
                float v[10];
#pragma unroll
                for (int j = 0; j < 10; ++j) v[j] = Cs[r * 162 + cl * 10 + j];
                float mx = v[0];
#pragma unroll
                for (int j = 1; j < 8; ++j) mx = fmaxf(mx, v[j]);
                float se = 0.f, sec = 0.f;
#pragma unroll
                for (int j = 0; j < 8; ++j) {
                    float e = __expf((v[j] - mx) * 20.0f);  // 1/SUB_T
                    se += e; sec += e * v[j];
                }
                float res = v[8] + v[9];
                if (c < NC)
                    out[(size_t)(r0 + p * 64 + r) * NC + c] =
                        (sec / se + res) * (1.0f / 0.07f);
            }
        }
    }
}

extern "C" void kernel_launch(void* const* d_in, const int* in_sizes, int n_in,
                              void* d_out, int out_size, void* d_ws, size_t ws_size,
                              hipStream_t stream) {
    (void)in_sizes; (void)n_in; (void)out_size; (void)ws_size;
    const float* h = (const float*)d_in[0];
    const float* protos = (const float*)d_in[1];
    float* out = (float*)d_out;
    float* ws = (float*)d_ws;

    float* X    = ws;                  // 512000  (Pn | centers | bvec)
    float* csum = X + 512000;          // 512
    float* M    = csum + 512;          // 10000   (Neumann matrix)
    float* T1   = M + 10000;           // 100000  [1000][100]
    float* T2   = T1 + 100000;         // 100000  [1000][100]
    float* Y    = T2 + 100000;         // 512000
    float* W    = Y + 512000;          // 51200
    unsigned short* hnb = (unsigned short*)(W + 51200);   // 32768*512 bf16
    unsigned short* Bp  = hnb + (size_t)NB * ND;          // 1120*512 bf16

    k_hn<<<NB / 4, 256, 0, stream>>>(h, hnb);
    k_prep_class<<<NC, 256, 0, stream>>>(protos, X);
    k_csum<<<2, 256, 0, stream>>>(X, csum);
    k_bopp<<<NC, 256, 0, stream>>>(X, csum);
    k_gram<<<NC, 128, 0, stream>>>(X, M);
    k_T1<<<1000, 128, 0, stream>>>(X, T1);
    k_T2neu<<<250, 256, 0, stream>>>(M, T1, T2);
    k_Y<<<1000, 256, 0, stream>>>(X, T2, Y);
    k_solve<<<NC, 256, 0, stream>>>(X, Y, W);
    k_packB<<<280, 256, 0, stream>>>(X, W, Bp);
    dim3 grid(7, NB / 128);
    k_main_mfma<<<grid, 256, 0, stream>>>(hnb, Bp, out);
}